// Round 1
// baseline (282.993 us; speedup 1.0000x reference)
//
#include <hip/hip_runtime.h>
#include <hip/hip_bf16.h>

#define NN 50000
#define NE 800000
#define HF 128
#define MAXDEG 64   // Poisson(16) tail: P(deg>=64) ~ 1e-20; clamped for safety

// workspace byte offsets (256-aligned); ws_size = 256 MiB
#define OFF_FLAG   0u
#define OFF_Z      16668672u    // 6,400,000 bf16
#define OFF_H1     29468672u    // 6,400,000 bf16
#define OFF_EL     42268672u    // 200000 f32
#define OFF_ER     43068672u    // 200000 f32
#define OFF_FILL   54000128u    // 50000 * 4 degree counters
#define OFF_ADJ2   60000000u    // 50000 * 64 * 4 = 12.8 MB fixed-capacity adjacency

typedef __hip_bfloat16 bf16;
typedef unsigned short us16;

#define SCAT_B 3125      // NE / 256, edge-scatter blocks fused into layer-1 GEMM
#define GEMM_B 782       // (NN + 63) / 64

typedef __attribute__((ext_vector_type(8))) short bf16x8;   // MFMA A/B frag
typedef __attribute__((ext_vector_type(4))) float f32x4;    // MFMA C/D frag

__device__ __forceinline__ float us2f(us16 u) {
  union { unsigned int i; float f; } c; c.i = ((unsigned int)u) << 16; return c.f;
}
__device__ __forceinline__ us16 f2us(float f) {
  bf16 h = __float2bfloat16(f);
  union { bf16 h; us16 u; } c; c.h = h; return c.u;
}
__device__ __forceinline__ float blo(unsigned v) {
  union { unsigned i; float f; } c; c.i = v << 16; return c.f;
}
__device__ __forceinline__ float bhi(unsigned v) {
  union { unsigned i; float f; } c; c.i = v & 0xffff0000u; return c.f;
}
__device__ __forceinline__ unsigned pk2(float a, float b) {
  return (unsigned)f2us(a) | ((unsigned)f2us(b) << 16);
}

// per-block dtype detection (W1's first 4KB, L2-broadcast)
__device__ __forceinline__ int detect_f32(const us16* __restrict__ u) {
  int t = threadIdx.x;
  int mx = 0;
  for (int i = t; i < 2048; i += 256) {
    int e = (u[i] >> 7) & 0xFF;
    mx = mx > e ? mx : e;
  }
#pragma unroll
  for (int m = 32; m >= 1; m >>= 1) {
    int o = __shfl_xor(mx, m);
    mx = mx > o ? mx : o;
  }
  __shared__ int sred[4];
  if ((t & 63) == 0) sred[t >> 6] = mx;
  __syncthreads();
  int a = sred[0] > sred[1] ? sred[0] : sred[1];
  int b = sred[2] > sred[3] ? sred[2] : sred[3];
  int r = a > b ? a : b;
  return r >= 135;
}

// ---- MFMA GEMM + fused el/er epilogue (16x16x32 bf16; W LDS-repacked B-frag order)
// LAYER 1: leading SCAT_B blocks do the edge scatter (rank+place adjacency build)
//          so the atomic long-pole overlaps MFMA work; GEMM blocks read RAW
//          feats/W1/al1/ar1 with flag-based f32->bf16 conversion (no canon pass).
// LAYER 2: X = h1 (internal bf16); W2/al2/ar2 raw, dtype from *flagp.
template <int LAYER>
__global__ __launch_bounds__(256) void k_gemm(
    const void* __restrict__ Xv, const void* __restrict__ Wv,
    const void* __restrict__ alr, const void* __restrict__ arr,
    us16* __restrict__ Z, float* __restrict__ el, float* __restrict__ er,
    const int* __restrict__ src, const int* __restrict__ dst,
    int* __restrict__ fill, int* __restrict__ adj2, int* __restrict__ flagp) {
  if (LAYER == 1) {
    if ((int)blockIdx.x < SCAT_B) {
      // edge scatter: SCAT_B*256 == NE exactly, no bounds check needed
      int e = blockIdx.x * 256 + threadIdx.x;
      int d = dst[e];
      int r = atomicAdd(&fill[d], 1);
      if (r < MAXDEG) adj2[(d << 6) + r] = src[e];
      return;
    }
  }
  int bx = (LAYER == 1) ? (int)blockIdx.x - SCAT_B : (int)blockIdx.x;

  __shared__ us16 Wl[HF * HF];
  int f;
  if (LAYER == 1) {
    f = detect_f32((const us16*)Wv);
    if (bx == 0 && threadIdx.x == 0) *flagp = f;
  } else {
    f = *flagp;  // uniform scalar load, written by layer-1 kernel
  }

  int tid = threadIdx.x;
  {
    const float* Wf = (const float*)Wv;
    const us16* Wb = (const us16*)Wv;
    for (int e = tid; e < HF * HF; e += 256) {
      int k = e >> 7, n = e & 127;
      int d = ((((k >> 5) * 8 + (n >> 4)) * 4 + ((k >> 3) & 3)) * 16 + (n & 15)) * 8 + (k & 7);
      Wl[d] = f ? f2us(Wf[e]) : Wb[e];
    }
  }
  __syncthreads();

  int w = tid >> 6;
  int lane = tid & 63;
  int q = lane >> 4;
  int c = lane & 15;
  int m0 = bx * 64 + w * 16;

  int rA = m0 + c;
  if (rA >= NN) rA = NN - 1;
  const us16* xb = (const us16*)Xv + (size_t)rA * HF;
  const float* xf = (const float*)Xv + (size_t)rA * HF;

  f32x4 acc[8] = {};
#pragma unroll
  for (int s = 0; s < 4; ++s) {
    bf16x8 a;
    if (LAYER == 1 && f) {
      float4 v0 = *(const float4*)&xf[s * 32 + q * 8];
      float4 v1 = *(const float4*)&xf[s * 32 + q * 8 + 4];
      union { us16 u[8]; bf16x8 v; } cv;
      cv.u[0] = f2us(v0.x); cv.u[1] = f2us(v0.y);
      cv.u[2] = f2us(v0.z); cv.u[3] = f2us(v0.w);
      cv.u[4] = f2us(v1.x); cv.u[5] = f2us(v1.y);
      cv.u[6] = f2us(v1.z); cv.u[7] = f2us(v1.w);
      a = cv.v;
    } else {
      a = *(const bf16x8*)&xb[s * 32 + q * 8];
    }
#pragma unroll
    for (int t = 0; t < 8; ++t) {
      bf16x8 bb = *(const bf16x8*)&Wl[((((s * 8) + t) * 4 + q) * 16 + c) * 8];
      acc[t] = __builtin_amdgcn_mfma_f32_16x16x32_bf16(a, bb, acc[t], 0, 0, 0);
    }
  }

#pragma unroll
  for (int reg = 0; reg < 4; ++reg) {
    int row = m0 + q * 4 + reg;
    if (row < NN) {
      us16* zrow = Z + (size_t)row * HF;
#pragma unroll
      for (int t = 0; t < 8; ++t) zrow[t * 16 + c] = f2us(acc[t][reg]);
    }
  }

  float alv[8], arv[8];
  {
    const float* alf = (const float*)alr; const us16* alb = (const us16*)alr;
    const float* arf = (const float*)arr; const us16* arb = (const us16*)arr;
#pragma unroll
    for (int t = 0; t < 8; ++t) {
      alv[t] = f ? alf[t * 16 + c] : us2f(alb[t * 16 + c]);
      arv[t] = f ? arf[t * 16 + c] : us2f(arb[t * 16 + c]);
    }
  }
#pragma unroll
  for (int reg = 0; reg < 4; ++reg) {
    int row = m0 + q * 4 + reg;
    float pl[4], pr[4];
#pragma unroll
    for (int h = 0; h < 4; ++h) {
      pl[h] = acc[2 * h][reg] * alv[2 * h] + acc[2 * h + 1][reg] * alv[2 * h + 1];
      pr[h] = acc[2 * h][reg] * arv[2 * h] + acc[2 * h + 1][reg] * arv[2 * h + 1];
    }
#pragma unroll
    for (int m = 1; m < 16; m <<= 1) {
#pragma unroll
      for (int h = 0; h < 4; ++h) {
        pl[h] += __shfl_xor(pl[h], m);
        pr[h] += __shfl_xor(pr[h], m);
      }
    }
    if (row < NN) {
      int cc = c & 3;
      float vl = cc == 0 ? pl[0] : cc == 1 ? pl[1] : cc == 2 ? pl[2] : pl[3];
      float vr = cc == 0 ? pr[0] : cc == 1 ? pr[1] : cc == 2 ? pr[2] : pr[3];
      if (c < 4) el[row * 4 + cc] = vl;
      else if (c < 8) er[row * 4 + cc] = vr;
    }
  }
}

// One wave per destination node; 4 nodes per 256-thread block (no barriers).
// Fixed-capacity adjacency: row n at adj2[n*64], deg = min(fill[n], 64).
// 2-wide unrolled edge loop. resid/bias/Wp/bp read RAW with flag-based dtype.
template <int LAYER>
__global__ __launch_bounds__(256) void k_agg(
    const us16* __restrict__ Z, const float* __restrict__ el,
    const float* __restrict__ er, const int* __restrict__ fill,
    const int* __restrict__ adj2, const void* __restrict__ resid,
    const void* __restrict__ bias, us16* __restrict__ Hout,
    const void* __restrict__ Wp, const void* __restrict__ bp,
    void* __restrict__ out, const int* __restrict__ flag) {
  int f = *flag;
  int n = blockIdx.x * 4 + (threadIdx.x >> 6);
  int lane = threadIdx.x & 63;
  int g = lane >> 4;
  int p = lane & 15;
  int hl = p >> 2;
  int f0 = p * 8;
  int deg = fill[n];
  if (deg > MAXDEG) deg = MAXDEG;
  int begin = n << 6;
  float erh = er[n * 4 + hl];

  float acc[8] = {};
  float ssum = 0.f;
  int i = g;
  for (; i + 4 < deg; i += 8) {
    int s0 = adj2[begin + i];
    int s1 = adj2[begin + i + 4];
    float l0 = el[s0 * 4 + hl];
    float l1 = el[s1 * 4 + hl];
    uint4 za = *(const uint4*)&Z[(size_t)s0 * HF + f0];
    uint4 zb = *(const uint4*)&Z[(size_t)s1 * HF + f0];
    float sc0 = l0 + erh; sc0 = sc0 > 0.f ? sc0 : 0.2f * sc0;
    float sc1 = l1 + erh; sc1 = sc1 > 0.f ? sc1 : 0.2f * sc1;
    float ex0 = __expf(sc0);
    float ex1 = __expf(sc1);
    ssum += ex0 + ex1;
    acc[0] = fmaf(ex0, blo(za.x), acc[0]); acc[1] = fmaf(ex0, bhi(za.x), acc[1]);
    acc[2] = fmaf(ex0, blo(za.y), acc[2]); acc[3] = fmaf(ex0, bhi(za.y), acc[3]);
    acc[4] = fmaf(ex0, blo(za.z), acc[4]); acc[5] = fmaf(ex0, bhi(za.z), acc[5]);
    acc[6] = fmaf(ex0, blo(za.w), acc[6]); acc[7] = fmaf(ex0, bhi(za.w), acc[7]);
    acc[0] = fmaf(ex1, blo(zb.x), acc[0]); acc[1] = fmaf(ex1, bhi(zb.x), acc[1]);
    acc[2] = fmaf(ex1, blo(zb.y), acc[2]); acc[3] = fmaf(ex1, bhi(zb.y), acc[3]);
    acc[4] = fmaf(ex1, blo(zb.z), acc[4]); acc[5] = fmaf(ex1, bhi(zb.z), acc[5]);
    acc[6] = fmaf(ex1, blo(zb.w), acc[6]); acc[7] = fmaf(ex1, bhi(zb.w), acc[7]);
  }
  if (i < deg) {
    int s = adj2[begin + i];
    float sc = el[s * 4 + hl] + erh;
    sc = sc > 0.f ? sc : 0.2f * sc;
    float ex = __expf(sc);
    ssum += ex;
    uint4 zq = *(const uint4*)&Z[(size_t)s * HF + f0];
    acc[0] = fmaf(ex, blo(zq.x), acc[0]); acc[1] = fmaf(ex, bhi(zq.x), acc[1]);
    acc[2] = fmaf(ex, blo(zq.y), acc[2]); acc[3] = fmaf(ex, bhi(zq.y), acc[3]);
    acc[4] = fmaf(ex, blo(zq.z), acc[4]); acc[5] = fmaf(ex, bhi(zq.z), acc[5]);
    acc[6] = fmaf(ex, blo(zq.w), acc[6]); acc[7] = fmaf(ex, bhi(zq.w), acc[7]);
  }
  ssum += __shfl_xor(ssum, 16); ssum += __shfl_xor(ssum, 32);
#pragma unroll
  for (int j = 0; j < 8; ++j) {
    acc[j] += __shfl_xor(acc[j], 16);
    acc[j] += __shfl_xor(acc[j], 32);
  }
  float inv = 1.f / fmaxf(ssum, 1e-9f);

  float rx[8];
  if (LAYER == 1 && f) {
    const float* rf = (const float*)resid + (size_t)n * HF + f0;
    float4 r0 = *(const float4*)rf;
    float4 r1 = *(const float4*)(rf + 4);
    rx[0] = r0.x; rx[1] = r0.y; rx[2] = r0.z; rx[3] = r0.w;
    rx[4] = r1.x; rx[5] = r1.y; rx[6] = r1.z; rx[7] = r1.w;
  } else {
    uint4 xq = *(const uint4*)((const us16*)resid + (size_t)n * HF + f0);
    rx[0] = blo(xq.x); rx[1] = bhi(xq.x); rx[2] = blo(xq.y); rx[3] = bhi(xq.y);
    rx[4] = blo(xq.z); rx[5] = bhi(xq.z); rx[6] = blo(xq.w); rx[7] = bhi(xq.w);
  }
  float bv[8];
  if (f) {
    const float* bf_ = (const float*)bias + f0;
    bv[0] = bf_[0]; bv[1] = bf_[1]; bv[2] = bf_[2]; bv[3] = bf_[3];
    bv[4] = bf_[4]; bv[5] = bf_[5]; bv[6] = bf_[6]; bv[7] = bf_[7];
  } else {
    uint4 bq = *(const uint4*)((const us16*)bias + f0);
    bv[0] = blo(bq.x); bv[1] = bhi(bq.x); bv[2] = blo(bq.y); bv[3] = bhi(bq.y);
    bv[4] = blo(bq.z); bv[5] = bhi(bq.z); bv[6] = blo(bq.w); bv[7] = bhi(bq.w);
  }
  float t0 = fmaf(acc[0], inv, rx[0] + bv[0]);
  float t1 = fmaf(acc[1], inv, rx[1] + bv[1]);
  float t2 = fmaf(acc[2], inv, rx[2] + bv[2]);
  float t3 = fmaf(acc[3], inv, rx[3] + bv[3]);
  float t4 = fmaf(acc[4], inv, rx[4] + bv[4]);
  float t5 = fmaf(acc[5], inv, rx[5] + bv[5]);
  float t6 = fmaf(acc[6], inv, rx[6] + bv[6]);
  float t7 = fmaf(acc[7], inv, rx[7] + bv[7]);

  if (LAYER == 1) {
    t0 = t0 > 0.f ? t0 : __expf(t0) - 1.f;
    t1 = t1 > 0.f ? t1 : __expf(t1) - 1.f;
    t2 = t2 > 0.f ? t2 : __expf(t2) - 1.f;
    t3 = t3 > 0.f ? t3 : __expf(t3) - 1.f;
    t4 = t4 > 0.f ? t4 : __expf(t4) - 1.f;
    t5 = t5 > 0.f ? t5 : __expf(t5) - 1.f;
    t6 = t6 > 0.f ? t6 : __expf(t6) - 1.f;
    t7 = t7 > 0.f ? t7 : __expf(t7) - 1.f;
    if (g == 0) {
      uint4 o;
      o.x = pk2(t0, t1); o.y = pk2(t2, t3); o.z = pk2(t4, t5); o.w = pk2(t6, t7);
      *(uint4*)&Hout[(size_t)n * HF + f0] = o;
    }
  } else {
    t0 += __shfl_xor(t0, 4); t0 += __shfl_xor(t0, 8);
    t1 += __shfl_xor(t1, 4); t1 += __shfl_xor(t1, 8);
    t2 += __shfl_xor(t2, 4); t2 += __shfl_xor(t2, 8);
    t3 += __shfl_xor(t3, 4); t3 += __shfl_xor(t3, 8);
    t4 += __shfl_xor(t4, 4); t4 += __shfl_xor(t4, 8);
    t5 += __shfl_xor(t5, 4); t5 += __shfl_xor(t5, 8);
    t6 += __shfl_xor(t6, 4); t6 += __shfl_xor(t6, 8);
    t7 += __shfl_xor(t7, 4); t7 += __shfl_xor(t7, 8);
    int fw = (p & 3) * 8;
    float wv0, wv1, wv2, wv3, wv4, wv5, wv6, wv7;
    if (f) {
      const float* wpf = (const float*)Wp;
      wv0 = wpf[fw];     wv1 = wpf[fw + 1]; wv2 = wpf[fw + 2]; wv3 = wpf[fw + 3];
      wv4 = wpf[fw + 4]; wv5 = wpf[fw + 5]; wv6 = wpf[fw + 6]; wv7 = wpf[fw + 7];
    } else {
      const us16* wpb = (const us16*)Wp;
      wv0 = us2f(wpb[fw]);     wv1 = us2f(wpb[fw + 1]);
      wv2 = us2f(wpb[fw + 2]); wv3 = us2f(wpb[fw + 3]);
      wv4 = us2f(wpb[fw + 4]); wv5 = us2f(wpb[fw + 5]);
      wv6 = us2f(wpb[fw + 6]); wv7 = us2f(wpb[fw + 7]);
    }
    float pr = 0.25f * (t0 * wv0 + t1 * wv1 + t2 * wv2 + t3 * wv3 +
                        t4 * wv4 + t5 * wv5 + t6 * wv6 + t7 * wv7);
    pr += __shfl_xor(pr, 1); pr += __shfl_xor(pr, 2);
    if (lane == 0) {
      float bpv = f ? ((const float*)bp)[0] : us2f(((const us16*)bp)[0]);
      float res = pr + bpv;
      if (f) ((float*)out)[n] = res;
      else ((us16*)out)[n] = f2us(res);
    }
  }
}

extern "C" void kernel_launch(void* const* d_in, const int* in_sizes, int n_in,
                              void* d_out, int out_size, void* d_ws, size_t ws_size,
                              hipStream_t stream) {
  const int* src = (const int*)d_in[1];
  const int* dst = (const int*)d_in[2];
  char* ws = (char*)d_ws;
  int* flag   = (int*)(ws + OFF_FLAG);
  us16* z     = (us16*)(ws + OFF_Z);
  us16* h1    = (us16*)(ws + OFF_H1);
  float* el   = (float*)(ws + OFF_EL);
  float* er   = (float*)(ws + OFF_ER);
  int* fill   = (int*)(ws + OFF_FILL);
  int* adj2   = (int*)(ws + OFF_ADJ2);

  hipMemsetAsync(fill, 0, (size_t)NN * 4, stream);  // zero degree counters

  // 1) layer-1 gemm, fused with edge scatter (leading SCAT_B blocks) +
  //    raw-input dtype conversion (no canonicalization pass)
  hipLaunchKernelGGL((k_gemm<1>), dim3(SCAT_B + GEMM_B), dim3(256), 0, stream,
                     d_in[0], d_in[3], d_in[4], d_in[5], z, el, er,
                     src, dst, fill, adj2, flag);
  // 2) layer-1 aggregation (residual+bias+ELU fused; raw feats residual)
  hipLaunchKernelGGL((k_agg<1>), dim3(NN / 4), dim3(256), 0, stream, z, el, er,
                     fill, adj2, d_in[0], d_in[6], h1,
                     (const void*)nullptr, (const void*)nullptr, (void*)nullptr, flag);
  // 3) layer-2 gemm (el/er epilogue; raw W2/al2/ar2, dtype from *flag)
  hipLaunchKernelGGL((k_gemm<2>), dim3(GEMM_B), dim3(256), 0, stream,
                     h1, d_in[7], d_in[8], d_in[9], z, el, er,
                     src, dst, fill, adj2, flag);
  // 4) layer-2 aggregation (+ head-mean + projection + bp)
  hipLaunchKernelGGL((k_agg<2>), dim3(NN / 4), dim3(256), 0, stream, z, el, er,
                     fill, adj2, h1, d_in[10], (us16*)nullptr,
                     d_in[11], d_in[12], d_out, flag);
}

// Round 2
// 268.982 us; speedup vs baseline: 1.0521x; 1.0521x over previous
//
#include <hip/hip_runtime.h>
#include <hip/hip_bf16.h>

#define NN 50000
#define NE 800000
#define HF 128
#define MAXDEG 64   // Poisson(16) tail: P(deg>=64) ~ 1e-20; clamped for safety

// workspace byte offsets (256-aligned); ws_size = 256 MiB
#define OFF_FLAG   0u
#define OFF_Z      16668672u    // 6,400,000 bf16
#define OFF_H1     29468672u    // 6,400,000 bf16
#define OFF_EL     42268672u    // 200000 f32
#define OFF_ER     43068672u    // 200000 f32
#define OFF_FILL   54000128u    // 50000 * 4 degree counters
#define OFF_ADJ2   60000000u    // 50000 * 64 * 2 = 6.4 MB fixed-capacity adjacency (us16)

typedef __hip_bfloat16 bf16;
typedef unsigned short us16;

#define GEMM_B 782       // (NN + 63) / 64; 782*256*4 = 800768 >= NE edge slots

typedef __attribute__((ext_vector_type(8))) short bf16x8;   // MFMA A/B frag
typedef __attribute__((ext_vector_type(4))) float f32x4;    // MFMA C/D frag

__device__ __forceinline__ float us2f(us16 u) {
  union { unsigned int i; float f; } c; c.i = ((unsigned int)u) << 16; return c.f;
}
__device__ __forceinline__ us16 f2us(float f) {
  bf16 h = __float2bfloat16(f);
  union { bf16 h; us16 u; } c; c.h = h; return c.u;
}
__device__ __forceinline__ float blo(unsigned v) {
  union { unsigned i; float f; } c; c.i = v << 16; return c.f;
}
__device__ __forceinline__ float bhi(unsigned v) {
  union { unsigned i; float f; } c; c.i = v & 0xffff0000u; return c.f;
}
__device__ __forceinline__ unsigned pk2(float a, float b) {
  return (unsigned)f2us(a) | ((unsigned)f2us(b) << 16);
}

// per-block dtype detection (W1's first 4KB, L2-broadcast)
__device__ __forceinline__ int detect_f32(const us16* __restrict__ u) {
  int t = threadIdx.x;
  int mx = 0;
  for (int i = t; i < 2048; i += 256) {
    int e = (u[i] >> 7) & 0xFF;
    mx = mx > e ? mx : e;
  }
#pragma unroll
  for (int m = 32; m >= 1; m >>= 1) {
    int o = __shfl_xor(mx, m);
    mx = mx > o ? mx : o;
  }
  __shared__ int sred[4];
  if ((t & 63) == 0) sred[t >> 6] = mx;
  __syncthreads();
  int a = sred[0] > sred[1] ? sred[0] : sred[1];
  int b = sred[2] > sred[3] ? sred[2] : sred[3];
  int r = a > b ? a : b;
  return r >= 135;
}

// ---- MFMA GEMM + fused el/er epilogue (16x16x32 bf16; W LDS-repacked B-frag order)
// LAYER 1: every block also scatters 4 edges/thread into the fixed-capacity
//          adjacency. Schedule: dst/src loads at top (latency under W-repack),
//          atomics issued after ALL gemm vmem loads are in registers (vmcnt
//          retires in-order -> no later load-wait stalls on the atomics),
//          adj2 stores at the very end (atomic latency hidden under MFMA).
// LAYER 2: X = h1 (internal bf16); W2/al2/ar2 raw, dtype from *flagp.
template <int LAYER>
__global__ __launch_bounds__(256) void k_gemm(
    const void* __restrict__ Xv, const void* __restrict__ Wv,
    const void* __restrict__ alr, const void* __restrict__ arr,
    us16* __restrict__ Z, float* __restrict__ el, float* __restrict__ er,
    const int* __restrict__ src, const int* __restrict__ dst,
    int* __restrict__ fill, us16* __restrict__ adj2, int* __restrict__ flagp) {
  int tid = threadIdx.x;
  int bx = (int)blockIdx.x;

  // --- edge scatter: stage index loads early
  int4 dstv = {0, 0, 0, 0}, srcv = {0, 0, 0, 0};
  bool ed = false;
  if (LAYER == 1) {
    int e0 = (bx * 256 + tid) * 4;
    if (e0 < NE) {  // NE % 4 == 0 -> quad fully in or out
      ed = true;
      dstv = *(const int4*)&dst[e0];
      srcv = *(const int4*)&src[e0];
    }
  }

  __shared__ us16 Wl[HF * HF];
  int f;
  if (LAYER == 1) {
    f = detect_f32((const us16*)Wv);
    if (bx == 0 && tid == 0) *flagp = f;
  } else {
    f = *flagp;  // uniform scalar load, written by layer-1 kernel
  }

  {
    const float* Wf = (const float*)Wv;
    const us16* Wb = (const us16*)Wv;
    for (int e = tid; e < HF * HF; e += 256) {
      int k = e >> 7, n = e & 127;
      int d = ((((k >> 5) * 8 + (n >> 4)) * 4 + ((k >> 3) & 3)) * 16 + (n & 15)) * 8 + (k & 7);
      Wl[d] = f ? f2us(Wf[e]) : Wb[e];
    }
  }
  __syncthreads();

  int w = tid >> 6;
  int lane = tid & 63;
  int q = lane >> 4;
  int c = lane & 15;
  int m0 = bx * 64 + w * 16;

  int rA = m0 + c;
  if (rA >= NN) rA = NN - 1;
  const us16* xb = (const us16*)Xv + (size_t)rA * HF;
  const float* xf = (const float*)Xv + (size_t)rA * HF;

  // --- preload ALL gemm vmem inputs into registers before issuing atomics
  bf16x8 afr[4];
#pragma unroll
  for (int s = 0; s < 4; ++s) {
    if (LAYER == 1 && f) {
      float4 v0 = *(const float4*)&xf[s * 32 + q * 8];
      float4 v1 = *(const float4*)&xf[s * 32 + q * 8 + 4];
      union { us16 u[8]; bf16x8 v; } cv;
      cv.u[0] = f2us(v0.x); cv.u[1] = f2us(v0.y);
      cv.u[2] = f2us(v0.z); cv.u[3] = f2us(v0.w);
      cv.u[4] = f2us(v1.x); cv.u[5] = f2us(v1.y);
      cv.u[6] = f2us(v1.z); cv.u[7] = f2us(v1.w);
      afr[s] = cv.v;
    } else {
      afr[s] = *(const bf16x8*)&xb[s * 32 + q * 8];
    }
  }
  float alv[8], arv[8];
  {
    const float* alf = (const float*)alr; const us16* alb = (const us16*)alr;
    const float* arf = (const float*)arr; const us16* arb = (const us16*)arr;
#pragma unroll
    for (int t = 0; t < 8; ++t) {
      alv[t] = f ? alf[t * 16 + c] : us2f(alb[t * 16 + c]);
      arv[t] = f ? arf[t * 16 + c] : us2f(arb[t * 16 + c]);
    }
  }

  // --- issue rank atomics; returns consumed only at kernel end
  int r0 = 0, r1 = 0, r2 = 0, r3 = 0;
  if (LAYER == 1 && ed) {
    r0 = atomicAdd(&fill[dstv.x], 1);
    r1 = atomicAdd(&fill[dstv.y], 1);
    r2 = atomicAdd(&fill[dstv.z], 1);
    r3 = atomicAdd(&fill[dstv.w], 1);
  }
  asm volatile("" ::: "memory");  // keep atomics here; don't sink toward use

  // --- MFMA loop: LDS reads only (lgkmcnt), no vmcnt waits -> atomics fly
  f32x4 acc[8] = {};
#pragma unroll
  for (int s = 0; s < 4; ++s) {
#pragma unroll
    for (int t = 0; t < 8; ++t) {
      bf16x8 bb = *(const bf16x8*)&Wl[((((s * 8) + t) * 4 + q) * 16 + c) * 8];
      acc[t] = __builtin_amdgcn_mfma_f32_16x16x32_bf16(afr[s], bb, acc[t], 0, 0, 0);
    }
  }

#pragma unroll
  for (int reg = 0; reg < 4; ++reg) {
    int row = m0 + q * 4 + reg;
    if (row < NN) {
      us16* zrow = Z + (size_t)row * HF;
#pragma unroll
      for (int t = 0; t < 8; ++t) zrow[t * 16 + c] = f2us(acc[t][reg]);
    }
  }

#pragma unroll
  for (int reg = 0; reg < 4; ++reg) {
    int row = m0 + q * 4 + reg;
    float pl[4], pr[4];
#pragma unroll
    for (int h = 0; h < 4; ++h) {
      pl[h] = acc[2 * h][reg] * alv[2 * h] + acc[2 * h + 1][reg] * alv[2 * h + 1];
      pr[h] = acc[2 * h][reg] * arv[2 * h] + acc[2 * h + 1][reg] * arv[2 * h + 1];
    }
#pragma unroll
    for (int m = 1; m < 16; m <<= 1) {
#pragma unroll
      for (int h = 0; h < 4; ++h) {
        pl[h] += __shfl_xor(pl[h], m);
        pr[h] += __shfl_xor(pr[h], m);
      }
    }
    if (row < NN) {
      int cc = c & 3;
      float vl = cc == 0 ? pl[0] : cc == 1 ? pl[1] : cc == 2 ? pl[2] : pl[3];
      float vr = cc == 0 ? pr[0] : cc == 1 ? pr[1] : cc == 2 ? pr[2] : pr[3];
      if (c < 4) el[row * 4 + cc] = vl;
      else if (c < 8) er[row * 4 + cc] = vr;
    }
  }

  // --- adj2 placement: waits on atomic returns (long since landed)
  if (LAYER == 1 && ed) {
    if (r0 < MAXDEG) adj2[(dstv.x << 6) + r0] = (us16)srcv.x;
    if (r1 < MAXDEG) adj2[(dstv.y << 6) + r1] = (us16)srcv.y;
    if (r2 < MAXDEG) adj2[(dstv.z << 6) + r2] = (us16)srcv.z;
    if (r3 < MAXDEG) adj2[(dstv.w << 6) + r3] = (us16)srcv.w;
  }
}

// One wave per destination node; 4 nodes per 256-thread block (no barriers).
// Fixed-capacity adjacency: row n at adj2[n*64] (us16), deg = min(fill[n], 64).
// 2-wide unrolled edge loop. resid/bias/Wp/bp read RAW with flag-based dtype.
template <int LAYER>
__global__ __launch_bounds__(256) void k_agg(
    const us16* __restrict__ Z, const float* __restrict__ el,
    const float* __restrict__ er, const int* __restrict__ fill,
    const us16* __restrict__ adj2, const void* __restrict__ resid,
    const void* __restrict__ bias, us16* __restrict__ Hout,
    const void* __restrict__ Wp, const void* __restrict__ bp,
    void* __restrict__ out, const int* __restrict__ flag) {
  int f = *flag;
  int n = blockIdx.x * 4 + (threadIdx.x >> 6);
  int lane = threadIdx.x & 63;
  int g = lane >> 4;
  int p = lane & 15;
  int hl = p >> 2;
  int f0 = p * 8;
  int deg = fill[n];
  if (deg > MAXDEG) deg = MAXDEG;
  int begin = n << 6;
  float erh = er[n * 4 + hl];

  float acc[8] = {};
  float ssum = 0.f;
  int i = g;
  for (; i + 4 < deg; i += 8) {
    int s0 = adj2[begin + i];
    int s1 = adj2[begin + i + 4];
    float l0 = el[s0 * 4 + hl];
    float l1 = el[s1 * 4 + hl];
    uint4 za = *(const uint4*)&Z[(size_t)s0 * HF + f0];
    uint4 zb = *(const uint4*)&Z[(size_t)s1 * HF + f0];
    float sc0 = l0 + erh; sc0 = sc0 > 0.f ? sc0 : 0.2f * sc0;
    float sc1 = l1 + erh; sc1 = sc1 > 0.f ? sc1 : 0.2f * sc1;
    float ex0 = __expf(sc0);
    float ex1 = __expf(sc1);
    ssum += ex0 + ex1;
    acc[0] = fmaf(ex0, blo(za.x), acc[0]); acc[1] = fmaf(ex0, bhi(za.x), acc[1]);
    acc[2] = fmaf(ex0, blo(za.y), acc[2]); acc[3] = fmaf(ex0, bhi(za.y), acc[3]);
    acc[4] = fmaf(ex0, blo(za.z), acc[4]); acc[5] = fmaf(ex0, bhi(za.z), acc[5]);
    acc[6] = fmaf(ex0, blo(za.w), acc[6]); acc[7] = fmaf(ex0, bhi(za.w), acc[7]);
    acc[0] = fmaf(ex1, blo(zb.x), acc[0]); acc[1] = fmaf(ex1, bhi(zb.x), acc[1]);
    acc[2] = fmaf(ex1, blo(zb.y), acc[2]); acc[3] = fmaf(ex1, bhi(zb.y), acc[3]);
    acc[4] = fmaf(ex1, blo(zb.z), acc[4]); acc[5] = fmaf(ex1, bhi(zb.z), acc[5]);
    acc[6] = fmaf(ex1, blo(zb.w), acc[6]); acc[7] = fmaf(ex1, bhi(zb.w), acc[7]);
  }
  if (i < deg) {
    int s = adj2[begin + i];
    float sc = el[s * 4 + hl] + erh;
    sc = sc > 0.f ? sc : 0.2f * sc;
    float ex = __expf(sc);
    ssum += ex;
    uint4 zq = *(const uint4*)&Z[(size_t)s * HF + f0];
    acc[0] = fmaf(ex, blo(zq.x), acc[0]); acc[1] = fmaf(ex, bhi(zq.x), acc[1]);
    acc[2] = fmaf(ex, blo(zq.y), acc[2]); acc[3] = fmaf(ex, bhi(zq.y), acc[3]);
    acc[4] = fmaf(ex, blo(zq.z), acc[4]); acc[5] = fmaf(ex, bhi(zq.z), acc[5]);
    acc[6] = fmaf(ex, blo(zq.w), acc[6]); acc[7] = fmaf(ex, bhi(zq.w), acc[7]);
  }
  ssum += __shfl_xor(ssum, 16); ssum += __shfl_xor(ssum, 32);
#pragma unroll
  for (int j = 0; j < 8; ++j) {
    acc[j] += __shfl_xor(acc[j], 16);
    acc[j] += __shfl_xor(acc[j], 32);
  }
  float inv = 1.f / fmaxf(ssum, 1e-9f);

  float rx[8];
  if (LAYER == 1 && f) {
    const float* rf = (const float*)resid + (size_t)n * HF + f0;
    float4 r0 = *(const float4*)rf;
    float4 r1 = *(const float4*)(rf + 4);
    rx[0] = r0.x; rx[1] = r0.y; rx[2] = r0.z; rx[3] = r0.w;
    rx[4] = r1.x; rx[5] = r1.y; rx[6] = r1.z; rx[7] = r1.w;
  } else {
    uint4 xq = *(const uint4*)((const us16*)resid + (size_t)n * HF + f0);
    rx[0] = blo(xq.x); rx[1] = bhi(xq.x); rx[2] = blo(xq.y); rx[3] = bhi(xq.y);
    rx[4] = blo(xq.z); rx[5] = bhi(xq.z); rx[6] = blo(xq.w); rx[7] = bhi(xq.w);
  }
  float bv[8];
  if (f) {
    const float* bf_ = (const float*)bias + f0;
    bv[0] = bf_[0]; bv[1] = bf_[1]; bv[2] = bf_[2]; bv[3] = bf_[3];
    bv[4] = bf_[4]; bv[5] = bf_[5]; bv[6] = bf_[6]; bv[7] = bf_[7];
  } else {
    uint4 bq = *(const uint4*)((const us16*)bias + f0);
    bv[0] = blo(bq.x); bv[1] = bhi(bq.x); bv[2] = blo(bq.y); bv[3] = bhi(bq.y);
    bv[4] = blo(bq.z); bv[5] = bhi(bq.z); bv[6] = blo(bq.w); bv[7] = bhi(bq.w);
  }
  float t0 = fmaf(acc[0], inv, rx[0] + bv[0]);
  float t1 = fmaf(acc[1], inv, rx[1] + bv[1]);
  float t2 = fmaf(acc[2], inv, rx[2] + bv[2]);
  float t3 = fmaf(acc[3], inv, rx[3] + bv[3]);
  float t4 = fmaf(acc[4], inv, rx[4] + bv[4]);
  float t5 = fmaf(acc[5], inv, rx[5] + bv[5]);
  float t6 = fmaf(acc[6], inv, rx[6] + bv[6]);
  float t7 = fmaf(acc[7], inv, rx[7] + bv[7]);

  if (LAYER == 1) {
    t0 = t0 > 0.f ? t0 : __expf(t0) - 1.f;
    t1 = t1 > 0.f ? t1 : __expf(t1) - 1.f;
    t2 = t2 > 0.f ? t2 : __expf(t2) - 1.f;
    t3 = t3 > 0.f ? t3 : __expf(t3) - 1.f;
    t4 = t4 > 0.f ? t4 : __expf(t4) - 1.f;
    t5 = t5 > 0.f ? t5 : __expf(t5) - 1.f;
    t6 = t6 > 0.f ? t6 : __expf(t6) - 1.f;
    t7 = t7 > 0.f ? t7 : __expf(t7) - 1.f;
    if (g == 0) {
      uint4 o;
      o.x = pk2(t0, t1); o.y = pk2(t2, t3); o.z = pk2(t4, t5); o.w = pk2(t6, t7);
      *(uint4*)&Hout[(size_t)n * HF + f0] = o;
    }
  } else {
    t0 += __shfl_xor(t0, 4); t0 += __shfl_xor(t0, 8);
    t1 += __shfl_xor(t1, 4); t1 += __shfl_xor(t1, 8);
    t2 += __shfl_xor(t2, 4); t2 += __shfl_xor(t2, 8);
    t3 += __shfl_xor(t3, 4); t3 += __shfl_xor(t3, 8);
    t4 += __shfl_xor(t4, 4); t4 += __shfl_xor(t4, 8);
    t5 += __shfl_xor(t5, 4); t5 += __shfl_xor(t5, 8);
    t6 += __shfl_xor(t6, 4); t6 += __shfl_xor(t6, 8);
    t7 += __shfl_xor(t7, 4); t7 += __shfl_xor(t7, 8);
    int fw = (p & 3) * 8;
    float wv0, wv1, wv2, wv3, wv4, wv5, wv6, wv7;
    if (f) {
      const float* wpf = (const float*)Wp;
      wv0 = wpf[fw];     wv1 = wpf[fw + 1]; wv2 = wpf[fw + 2]; wv3 = wpf[fw + 3];
      wv4 = wpf[fw + 4]; wv5 = wpf[fw + 5]; wv6 = wpf[fw + 6]; wv7 = wpf[fw + 7];
    } else {
      const us16* wpb = (const us16*)Wp;
      wv0 = us2f(wpb[fw]);     wv1 = us2f(wpb[fw + 1]);
      wv2 = us2f(wpb[fw + 2]); wv3 = us2f(wpb[fw + 3]);
      wv4 = us2f(wpb[fw + 4]); wv5 = us2f(wpb[fw + 5]);
      wv6 = us2f(wpb[fw + 6]); wv7 = us2f(wpb[fw + 7]);
    }
    float pr = 0.25f * (t0 * wv0 + t1 * wv1 + t2 * wv2 + t3 * wv3 +
                        t4 * wv4 + t5 * wv5 + t6 * wv6 + t7 * wv7);
    pr += __shfl_xor(pr, 1); pr += __shfl_xor(pr, 2);
    if (lane == 0) {
      float bpv = f ? ((const float*)bp)[0] : us2f(((const us16*)bp)[0]);
      float res = pr + bpv;
      if (f) ((float*)out)[n] = res;
      else ((us16*)out)[n] = f2us(res);
    }
  }
}

extern "C" void kernel_launch(void* const* d_in, const int* in_sizes, int n_in,
                              void* d_out, int out_size, void* d_ws, size_t ws_size,
                              hipStream_t stream) {
  const int* src = (const int*)d_in[1];
  const int* dst = (const int*)d_in[2];
  char* ws = (char*)d_ws;
  int* flag   = (int*)(ws + OFF_FLAG);
  us16* z     = (us16*)(ws + OFF_Z);
  us16* h1    = (us16*)(ws + OFF_H1);
  float* el   = (float*)(ws + OFF_EL);
  float* er   = (float*)(ws + OFF_ER);
  int* fill   = (int*)(ws + OFF_FILL);
  us16* adj2  = (us16*)(ws + OFF_ADJ2);

  hipMemsetAsync(fill, 0, (size_t)NN * 4, stream);  // zero degree counters

  // 1) layer-1 gemm with edge scatter fused INTO the gemm blocks (4 edges/thread,
  //    atomic latency hidden under MFMA; no low-occupancy scatter-only blocks)
  hipLaunchKernelGGL((k_gemm<1>), dim3(GEMM_B), dim3(256), 0, stream,
                     d_in[0], d_in[3], d_in[4], d_in[5], z, el, er,
                     src, dst, fill, adj2, flag);
  // 2) layer-1 aggregation (residual+bias+ELU fused; raw feats residual)
  hipLaunchKernelGGL((k_agg<1>), dim3(NN / 4), dim3(256), 0, stream, z, el, er,
                     fill, adj2, d_in[0], d_in[6], h1,
                     (const void*)nullptr, (const void*)nullptr, (void*)nullptr, flag);
  // 3) layer-2 gemm (el/er epilogue; raw W2/al2/ar2, dtype from *flag)
  hipLaunchKernelGGL((k_gemm<2>), dim3(GEMM_B), dim3(256), 0, stream,
                     h1, d_in[7], d_in[8], d_in[9], z, el, er,
                     src, dst, fill, adj2, flag);
  // 4) layer-2 aggregation (+ head-mean + projection + bp)
  hipLaunchKernelGGL((k_agg<2>), dim3(NN / 4), dim3(256), 0, stream, z, el, er,
                     fill, adj2, h1, d_in[10], (us16*)nullptr,
                     d_in[11], d_in[12], d_out, flag);
}

// Round 4
// 268.348 us; speedup vs baseline: 1.0546x; 1.0024x over previous
//
#include <hip/hip_runtime.h>
#include <hip/hip_bf16.h>

#define NN 50000
#define NE 800000
#define HF 128
#define MAXDEG 64   // Poisson(16) tail: P(deg>=64) ~ 1e-20; clamped for safety

// workspace byte offsets (256-aligned); ws_size = 256 MiB
#define OFF_FLAG   0u
#define OFF_Z      16668672u    // 6,400,000 bf16
#define OFF_H1     29468672u    // 6,400,000 bf16
#define OFF_EL     42268672u    // 200000 f32
#define OFF_ER     43068672u    // 200000 f32
#define OFF_FILL   54000128u    // 50000 * 4 degree counters
#define OFF_ADJ2   60000000u    // 50000 * 64 * 2 = 6.4 MB fixed-capacity adjacency (us16)

typedef __hip_bfloat16 bf16;
typedef unsigned short us16;

#define SCAT_B 3125      // NE / 256, dedicated scatter grid (1 edge/thread)
#define GEMM_B 782       // (NN + 63) / 64

typedef __attribute__((ext_vector_type(8))) short bf16x8;   // MFMA A/B frag
typedef __attribute__((ext_vector_type(4))) float f32x4;    // MFMA C/D frag

__device__ __forceinline__ float us2f(us16 u) {
  union { unsigned int i; float f; } c; c.i = ((unsigned int)u) << 16; return c.f;
}
__device__ __forceinline__ us16 f2us(float f) {
  bf16 h = __float2bfloat16(f);
  union { bf16 h; us16 u; } c; c.h = h; return c.u;
}
__device__ __forceinline__ float blo(unsigned v) {
  union { unsigned i; float f; } c; c.i = v << 16; return c.f;
}
__device__ __forceinline__ float bhi(unsigned v) {
  union { unsigned i; float f; } c; c.i = v & 0xffff0000u; return c.f;
}
__device__ __forceinline__ unsigned pk2(float a, float b) {
  return (unsigned)f2us(a) | ((unsigned)f2us(b) << 16);
}

// per-block dtype detection (W1's first 4KB, L2-broadcast)
__device__ __forceinline__ int detect_f32(const us16* __restrict__ u) {
  int t = threadIdx.x;
  int mx = 0;
  for (int i = t; i < 2048; i += 256) {
    int e = (u[i] >> 7) & 0xFF;
    mx = mx > e ? mx : e;
  }
#pragma unroll
  for (int m = 32; m >= 1; m >>= 1) {
    int o = __shfl_xor(mx, m);
    mx = mx > o ? mx : o;
  }
  __shared__ int sred[4];
  if ((t & 63) == 0) sred[t >> 6] = mx;
  __syncthreads();
  int a = sred[0] > sred[1] ? sred[0] : sred[1];
  int b = sred[2] > sred[3] ? sred[2] : sred[3];
  int r = a > b ? a : b;
  return r >= 135;
}

// ---- dedicated edge scatter: 1 edge/thread, tiny kernel, max occupancy.
// Memory-side atomic service is the roofline; high wave count pipelines the
// dependent adj2 stores under later waves' atomics.
__global__ __launch_bounds__(256) void k_scatter(
    const int* __restrict__ src, const int* __restrict__ dst,
    int* __restrict__ fill, us16* __restrict__ adj2) {
  int e = blockIdx.x * 256 + threadIdx.x;  // SCAT_B*256 == NE exactly
  int d = dst[e];
  int r = atomicAdd(&fill[d], 1);
  if (r < MAXDEG) adj2[(d << 6) + r] = (us16)src[e];
}

// ---- MFMA GEMM + fused el/er epilogue (16x16x32 bf16; W LDS-repacked B-frag order)
// LAYER 1: X = raw feats (flag-based f32->bf16 at A-load; no canon pass)
// LAYER 2: X = h1 (internal bf16); W/al/ar raw, dtype from *flagp.
template <int LAYER>
__global__ __launch_bounds__(256) void k_gemm(
    const void* __restrict__ Xv, const void* __restrict__ Wv,
    const void* __restrict__ alr, const void* __restrict__ arr,
    us16* __restrict__ Z, float* __restrict__ el, float* __restrict__ er,
    int* __restrict__ flagp) {
  int tid = threadIdx.x;
  int bx = (int)blockIdx.x;

  __shared__ us16 Wl[HF * HF];
  int f;
  if (LAYER == 1) {
    f = detect_f32((const us16*)Wv);
    if (bx == 0 && tid == 0) *flagp = f;
  } else {
    f = *flagp;  // uniform scalar load, written by layer-1 kernel
  }

  {
    const float* Wf = (const float*)Wv;
    const us16* Wb = (const us16*)Wv;
    for (int e = tid; e < HF * HF; e += 256) {
      int k = e >> 7, n = e & 127;
      int d = ((((k >> 5) * 8 + (n >> 4)) * 4 + ((k >> 3) & 3)) * 16 + (n & 15)) * 8 + (k & 7);
      Wl[d] = f ? f2us(Wf[e]) : Wb[e];
    }
  }
  __syncthreads();

  int w = tid >> 6;
  int lane = tid & 63;
  int q = lane >> 4;
  int c = lane & 15;
  int m0 = bx * 64 + w * 16;

  int rA = m0 + c;
  if (rA >= NN) rA = NN - 1;
  const us16* xb = (const us16*)Xv + (size_t)rA * HF;
  const float* xf = (const float*)Xv + (size_t)rA * HF;

  f32x4 acc[8] = {};
#pragma unroll
  for (int s = 0; s < 4; ++s) {
    bf16x8 a;
    if (LAYER == 1 && f) {
      float4 v0 = *(const float4*)&xf[s * 32 + q * 8];
      float4 v1 = *(const float4*)&xf[s * 32 + q * 8 + 4];
      union { us16 u[8]; bf16x8 v; } cv;
      cv.u[0] = f2us(v0.x); cv.u[1] = f2us(v0.y);
      cv.u[2] = f2us(v0.z); cv.u[3] = f2us(v0.w);
      cv.u[4] = f2us(v1.x); cv.u[5] = f2us(v1.y);
      cv.u[6] = f2us(v1.z); cv.u[7] = f2us(v1.w);
      a = cv.v;
    } else {
      a = *(const bf16x8*)&xb[s * 32 + q * 8];
    }
#pragma unroll
    for (int t = 0; t < 8; ++t) {
      bf16x8 bb = *(const bf16x8*)&Wl[((((s * 8) + t) * 4 + q) * 16 + c) * 8];
      acc[t] = __builtin_amdgcn_mfma_f32_16x16x32_bf16(a, bb, acc[t], 0, 0, 0);
    }
  }

#pragma unroll
  for (int reg = 0; reg < 4; ++reg) {
    int row = m0 + q * 4 + reg;
    if (row < NN) {
      us16* zrow = Z + (size_t)row * HF;
#pragma unroll
      for (int t = 0; t < 8; ++t) zrow[t * 16 + c] = f2us(acc[t][reg]);
    }
  }

  float alv[8], arv[8];
  {
    const float* alf = (const float*)alr; const us16* alb = (const us16*)alr;
    const float* arf = (const float*)arr; const us16* arb = (const us16*)arr;
#pragma unroll
    for (int t = 0; t < 8; ++t) {
      alv[t] = f ? alf[t * 16 + c] : us2f(alb[t * 16 + c]);
      arv[t] = f ? arf[t * 16 + c] : us2f(arb[t * 16 + c]);
    }
  }
#pragma unroll
  for (int reg = 0; reg < 4; ++reg) {
    int row = m0 + q * 4 + reg;
    float pl[4], pr[4];
#pragma unroll
    for (int h = 0; h < 4; ++h) {
      pl[h] = acc[2 * h][reg] * alv[2 * h] + acc[2 * h + 1][reg] * alv[2 * h + 1];
      pr[h] = acc[2 * h][reg] * arv[2 * h] + acc[2 * h + 1][reg] * arv[2 * h + 1];
    }
#pragma unroll
    for (int m = 1; m < 16; m <<= 1) {
#pragma unroll
      for (int h = 0; h < 4; ++h) {
        pl[h] += __shfl_xor(pl[h], m);
        pr[h] += __shfl_xor(pr[h], m);
      }
    }
    if (row < NN) {
      int cc = c & 3;
      float vl = cc == 0 ? pl[0] : cc == 1 ? pl[1] : cc == 2 ? pl[2] : pl[3];
      float vr = cc == 0 ? pr[0] : cc == 1 ? pr[1] : cc == 2 ? pr[2] : pr[3];
      if (c < 4) el[row * 4 + cc] = vl;
      else if (c < 8) er[row * 4 + cc] = vr;
    }
  }
}

// One wave per destination node; 4 nodes per 256-thread block (no barriers).
// Adjacency row (64 us16 slots) prefetched into registers with ONE coalesced
// 128B load (lane l holds slot l); the edge loop broadcasts s via __shfl.
// CRITICAL: the loop trip count is WAVE-UNIFORM (k*8 < deg; deg is per-node,
// shared by all 64 lanes) so every __shfl executes with ALL lanes active --
// ds_bpermute from an EXEC-masked source lane returns undefined data (the R3
// bug). Invalid slots are predicated out: s clamped to 0 (garbage slot ids
// could index NaN-poisoned workspace), ex gated to 0.
template <int LAYER>
__global__ __launch_bounds__(256) void k_agg(
    const us16* __restrict__ Z, const float* __restrict__ el,
    const float* __restrict__ er, const int* __restrict__ fill,
    const us16* __restrict__ adj2, const void* __restrict__ resid,
    const void* __restrict__ bias, us16* __restrict__ Hout,
    const void* __restrict__ Wp, const void* __restrict__ bp,
    void* __restrict__ out, const int* __restrict__ flag) {
  int f = *flag;
  int n = blockIdx.x * 4 + (threadIdx.x >> 6);
  int lane = threadIdx.x & 63;
  int g = lane >> 4;
  int p = lane & 15;
  int hl = p >> 2;
  int f0 = p * 8;
  int begin = n << 6;

  // register-resident adjacency row: lane l holds slot l
  int sl = (int)adj2[begin + lane];

  int deg = fill[n];
  if (deg > MAXDEG) deg = MAXDEG;
  float erh = er[n * 4 + hl];

  float acc[8] = {};
  float ssum = 0.f;
  for (int k = 0; k * 8 < deg; ++k) {  // uniform trip count across the wave
    int i0 = g + k * 8;                 // <= 59 for deg <= 64
    int i1 = i0 + 4;                    // <= 63
    int s0 = __shfl(sl, i0);            // all 64 lanes active here
    int s1 = __shfl(sl, i1);
    bool v0 = i0 < deg;
    bool v1 = i1 < deg;
    s0 = v0 ? s0 : 0;
    s1 = v1 ? s1 : 0;
    float l0 = el[s0 * 4 + hl];
    float l1 = el[s1 * 4 + hl];
    uint4 za = *(const uint4*)&Z[(size_t)s0 * HF + f0];
    uint4 zb = *(const uint4*)&Z[(size_t)s1 * HF + f0];
    float sc0 = l0 + erh; sc0 = sc0 > 0.f ? sc0 : 0.2f * sc0;
    float sc1 = l1 + erh; sc1 = sc1 > 0.f ? sc1 : 0.2f * sc1;
    float ex0 = v0 ? __expf(sc0) : 0.f;
    float ex1 = v1 ? __expf(sc1) : 0.f;
    ssum += ex0 + ex1;
    acc[0] = fmaf(ex0, blo(za.x), acc[0]); acc[1] = fmaf(ex0, bhi(za.x), acc[1]);
    acc[2] = fmaf(ex0, blo(za.y), acc[2]); acc[3] = fmaf(ex0, bhi(za.y), acc[3]);
    acc[4] = fmaf(ex0, blo(za.z), acc[4]); acc[5] = fmaf(ex0, bhi(za.z), acc[5]);
    acc[6] = fmaf(ex0, blo(za.w), acc[6]); acc[7] = fmaf(ex0, bhi(za.w), acc[7]);
    acc[0] = fmaf(ex1, blo(zb.x), acc[0]); acc[1] = fmaf(ex1, bhi(zb.x), acc[1]);
    acc[2] = fmaf(ex1, blo(zb.y), acc[2]); acc[3] = fmaf(ex1, bhi(zb.y), acc[3]);
    acc[4] = fmaf(ex1, blo(zb.z), acc[4]); acc[5] = fmaf(ex1, bhi(zb.z), acc[5]);
    acc[6] = fmaf(ex1, blo(zb.w), acc[6]); acc[7] = fmaf(ex1, bhi(zb.w), acc[7]);
  }
  ssum += __shfl_xor(ssum, 16); ssum += __shfl_xor(ssum, 32);
#pragma unroll
  for (int j = 0; j < 8; ++j) {
    acc[j] += __shfl_xor(acc[j], 16);
    acc[j] += __shfl_xor(acc[j], 32);
  }
  float inv = 1.f / fmaxf(ssum, 1e-9f);

  float rx[8];
  if (LAYER == 1 && f) {
    const float* rf = (const float*)resid + (size_t)n * HF + f0;
    float4 r0 = *(const float4*)rf;
    float4 r1 = *(const float4*)(rf + 4);
    rx[0] = r0.x; rx[1] = r0.y; rx[2] = r0.z; rx[3] = r0.w;
    rx[4] = r1.x; rx[5] = r1.y; rx[6] = r1.z; rx[7] = r1.w;
  } else {
    uint4 xq = *(const uint4*)((const us16*)resid + (size_t)n * HF + f0);
    rx[0] = blo(xq.x); rx[1] = bhi(xq.x); rx[2] = blo(xq.y); rx[3] = bhi(xq.y);
    rx[4] = blo(xq.z); rx[5] = bhi(xq.z); rx[6] = blo(xq.w); rx[7] = bhi(xq.w);
  }
  float bv[8];
  if (f) {
    const float* bf_ = (const float*)bias + f0;
    bv[0] = bf_[0]; bv[1] = bf_[1]; bv[2] = bf_[2]; bv[3] = bf_[3];
    bv[4] = bf_[4]; bv[5] = bf_[5]; bv[6] = bf_[6]; bv[7] = bf_[7];
  } else {
    uint4 bq = *(const uint4*)((const us16*)bias + f0);
    bv[0] = blo(bq.x); bv[1] = bhi(bq.x); bv[2] = blo(bq.y); bv[3] = bhi(bq.y);
    bv[4] = blo(bq.z); bv[5] = bhi(bq.z); bv[6] = blo(bq.w); bv[7] = bhi(bq.w);
  }
  float t0 = fmaf(acc[0], inv, rx[0] + bv[0]);
  float t1 = fmaf(acc[1], inv, rx[1] + bv[1]);
  float t2 = fmaf(acc[2], inv, rx[2] + bv[2]);
  float t3 = fmaf(acc[3], inv, rx[3] + bv[3]);
  float t4 = fmaf(acc[4], inv, rx[4] + bv[4]);
  float t5 = fmaf(acc[5], inv, rx[5] + bv[5]);
  float t6 = fmaf(acc[6], inv, rx[6] + bv[6]);
  float t7 = fmaf(acc[7], inv, rx[7] + bv[7]);

  if (LAYER == 1) {
    t0 = t0 > 0.f ? t0 : __expf(t0) - 1.f;
    t1 = t1 > 0.f ? t1 : __expf(t1) - 1.f;
    t2 = t2 > 0.f ? t2 : __expf(t2) - 1.f;
    t3 = t3 > 0.f ? t3 : __expf(t3) - 1.f;
    t4 = t4 > 0.f ? t4 : __expf(t4) - 1.f;
    t5 = t5 > 0.f ? t5 : __expf(t5) - 1.f;
    t6 = t6 > 0.f ? t6 : __expf(t6) - 1.f;
    t7 = t7 > 0.f ? t7 : __expf(t7) - 1.f;
    if (g == 0) {
      uint4 o;
      o.x = pk2(t0, t1); o.y = pk2(t2, t3); o.z = pk2(t4, t5); o.w = pk2(t6, t7);
      *(uint4*)&Hout[(size_t)n * HF + f0] = o;
    }
  } else {
    t0 += __shfl_xor(t0, 4); t0 += __shfl_xor(t0, 8);
    t1 += __shfl_xor(t1, 4); t1 += __shfl_xor(t1, 8);
    t2 += __shfl_xor(t2, 4); t2 += __shfl_xor(t2, 8);
    t3 += __shfl_xor(t3, 4); t3 += __shfl_xor(t3, 8);
    t4 += __shfl_xor(t4, 4); t4 += __shfl_xor(t4, 8);
    t5 += __shfl_xor(t5, 4); t5 += __shfl_xor(t5, 8);
    t6 += __shfl_xor(t6, 4); t6 += __shfl_xor(t6, 8);
    t7 += __shfl_xor(t7, 4); t7 += __shfl_xor(t7, 8);
    int fw = (p & 3) * 8;
    float wv0, wv1, wv2, wv3, wv4, wv5, wv6, wv7;
    if (f) {
      const float* wpf = (const float*)Wp;
      wv0 = wpf[fw];     wv1 = wpf[fw + 1]; wv2 = wpf[fw + 2]; wv3 = wpf[fw + 3];
      wv4 = wpf[fw + 4]; wv5 = wpf[fw + 5]; wv6 = wpf[fw + 6]; wv7 = wpf[fw + 7];
    } else {
      const us16* wpb = (const us16*)Wp;
      wv0 = us2f(wpb[fw]);     wv1 = us2f(wpb[fw + 1]);
      wv2 = us2f(wpb[fw + 2]); wv3 = us2f(wpb[fw + 3]);
      wv4 = us2f(wpb[fw + 4]); wv5 = us2f(wpb[fw + 5]);
      wv6 = us2f(wpb[fw + 6]); wv7 = us2f(wpb[fw + 7]);
    }
    float pr = 0.25f * (t0 * wv0 + t1 * wv1 + t2 * wv2 + t3 * wv3 +
                        t4 * wv4 + t5 * wv5 + t6 * wv6 + t7 * wv7);
    pr += __shfl_xor(pr, 1); pr += __shfl_xor(pr, 2);
    if (lane == 0) {
      float bpv = f ? ((const float*)bp)[0] : us2f(((const us16*)bp)[0]);
      float res = pr + bpv;
      if (f) ((float*)out)[n] = res;
      else ((us16*)out)[n] = f2us(res);
    }
  }
}

extern "C" void kernel_launch(void* const* d_in, const int* in_sizes, int n_in,
                              void* d_out, int out_size, void* d_ws, size_t ws_size,
                              hipStream_t stream) {
  const int* src = (const int*)d_in[1];
  const int* dst = (const int*)d_in[2];
  char* ws = (char*)d_ws;
  int* flag   = (int*)(ws + OFF_FLAG);
  us16* z     = (us16*)(ws + OFF_Z);
  us16* h1    = (us16*)(ws + OFF_H1);
  float* el   = (float*)(ws + OFF_EL);
  float* er   = (float*)(ws + OFF_ER);
  int* fill   = (int*)(ws + OFF_FILL);
  us16* adj2  = (us16*)(ws + OFF_ADJ2);

  hipMemsetAsync(fill, 0, (size_t)NN * 4, stream);  // zero degree counters

  // 1) dedicated edge scatter (atomic-service roofline; max wave pipelining)
  hipLaunchKernelGGL(k_scatter, dim3(SCAT_B), dim3(256), 0, stream,
                     src, dst, fill, adj2);
  // 2) layer-1 gemm (el/er epilogue; raw feats/W1/al1/ar1)
  hipLaunchKernelGGL((k_gemm<1>), dim3(GEMM_B), dim3(256), 0, stream,
                     d_in[0], d_in[3], d_in[4], d_in[5], z, el, er, flag);
  // 3) layer-1 aggregation (residual+bias+ELU fused; raw feats residual)
  hipLaunchKernelGGL((k_agg<1>), dim3(NN / 4), dim3(256), 0, stream, z, el, er,
                     fill, adj2, d_in[0], d_in[6], h1,
                     (const void*)nullptr, (const void*)nullptr, (void*)nullptr, flag);
  // 4) layer-2 gemm (el/er epilogue; raw W2/al2/ar2, dtype from *flag)
  hipLaunchKernelGGL((k_gemm<2>), dim3(GEMM_B), dim3(256), 0, stream,
                     h1, d_in[7], d_in[8], d_in[9], z, el, er, flag);
  // 5) layer-2 aggregation (+ head-mean + projection + bp)
  hipLaunchKernelGGL((k_agg<2>), dim3(NN / 4), dim3(256), 0, stream, z, el, er,
                     fill, adj2, h1, d_in[10], (us16*)nullptr,
                     d_in[11], d_in[12], d_out, flag);
}